// Round 7
// baseline (173.530 us; speedup 1.0000x reference)
//
#include <hip/hip_runtime.h>
#include <math.h>

// Problem constants
#define B_ 256
#define M_ 512
#define D_ 768
#define H_ 8
#define DH_ 96
#define C_ 768

typedef float  f32x4_t __attribute__((ext_vector_type(4)));
typedef short  s16x8   __attribute__((ext_vector_type(8)));
typedef short  s16x4   __attribute__((ext_vector_type(4)));
typedef unsigned short u16;

__device__ __forceinline__ u16 cvt_bf16(float f) {
    union { float f; unsigned int u; } v; v.f = f;
    unsigned int r = (v.u + 0x7FFFu + ((v.u >> 16) & 1u)) >> 16;
    return (u16)r;
}
__device__ __forceinline__ float bf16_f32(u16 h) {
    union { unsigned int u; float f; } v; v.u = ((unsigned int)h) << 16;
    return v.f;
}

#define ACC_INIT {{0,0,0,0},{0,0,0,0},{0,0,0,0},{0,0,0,0}}
#define SCALE_ 0.10206207261596577f   // 1/sqrt(96)

// ---------------------------------------------------------------------------
// 64x64 bf16 MFMA GEMM core (proven round-5): tile = A(64xK) @ B(64xK)^T.
// ---------------------------------------------------------------------------
template<int BK>
__device__ __forceinline__ void mm64b(
    const u16* __restrict__ A, int lda, const u16* __restrict__ B, int ldb,
    int ksteps, int bRowClamp, u16* lA, u16* lB, f32x4_t* acc, int nfrag)
{
    constexpr int NL = BK / 32;
    const int t = threadIdx.x;
    const int srow = t >> 2, kq = t & 3;
    const int l = t & 63, w = t >> 6;
    const int brow = srow < bRowClamp ? srow : bRowClamp;

    for (int ks = 0; ks < ksteps; ++ks) {
        s16x8 va[NL], vb[NL];
        #pragma unroll
        for (int c = 0; c < NL; ++c) {
            const int ko = ks * BK + (kq * NL + c) * 8;
            va[c] = *reinterpret_cast<const s16x8*>(A + (size_t)srow * lda + ko);
            vb[c] = *reinterpret_cast<const s16x8*>(B + (size_t)brow * ldb + ko);
        }
        __syncthreads();
        #pragma unroll
        for (int c = 0; c < NL; ++c) {
            const int kb = kq * NL + c;
            *reinterpret_cast<s16x8*>(lA + (kb * 64 + srow) * 8) = va[c];
            *reinterpret_cast<s16x8*>(lB + (kb * 64 + srow) * 8) = vb[c];
        }
        __syncthreads();
        #pragma unroll
        for (int ksub = 0; ksub < NL; ++ksub) {
            const int kb = (l >> 4) + ksub * 4;
            s16x8 af = *reinterpret_cast<const s16x8*>(lA + (kb * 64 + w * 16 + (l & 15)) * 8);
            #pragma unroll
            for (int nb = 0; nb < 4; ++nb) {
                if (nb < nfrag) {
                    s16x8 bf = *reinterpret_cast<const s16x8*>(lB + (kb * 64 + nb * 16 + (l & 15)) * 8);
                    acc[nb] = __builtin_amdgcn_mfma_f32_16x16x32_bf16(af, bf, acc[nb], 0, 0, 0);
                }
            }
        }
    }
}

// C/D layout: col = lane&15, row = (lane>>4)*4 + reg (within wave's 16-row slice).
__device__ __forceinline__ void epilogue_f32(
    const f32x4_t* acc, float* out, int ldo, int m0, int n0,
    const float* bias, int act, int nfrag)
{
    const int t = threadIdx.x, l = t & 63, w = t >> 6;
    const int mbase = m0 + w * 16 + (l >> 4) * 4;
    #pragma unroll
    for (int nb = 0; nb < 4; ++nb) {
        if (nb >= nfrag) break;
        const int col = n0 + nb * 16 + (l & 15);
        const float bv = bias ? bias[col] : 0.0f;
        #pragma unroll
        for (int r = 0; r < 4; ++r) {
            float v = acc[nb][r] + bv;
            if (act) v = 1.0f / (1.0f + expf(-v));
            out[(size_t)(mbase + r) * ldo + col] = v;
        }
    }
}

__device__ __forceinline__ void epilogue_bf16(
    const f32x4_t* acc, u16* out, int ldo, int m0, int n0,
    const float* bias, int nfrag)
{
    const int t = threadIdx.x, l = t & 63, w = t >> 6;
    const int mbase = m0 + w * 16 + (l >> 4) * 4;
    #pragma unroll
    for (int nb = 0; nb < 4; ++nb) {
        if (nb >= nfrag) break;
        const int col = n0 + nb * 16 + (l & 15);
        const float bv = bias ? bias[col] : 0.0f;
        #pragma unroll
        for (int r = 0; r < 4; ++r)
            out[(size_t)(mbase + r) * ldo + col] = cvt_bf16(acc[nb][r] + bv);
    }
}

// ---------------------------------------------------------------------------
// mmT64: 64x64 MFMA GEMM, f32 inputs, B accessed TRANSPOSED:
//   out[m,n] = sum_k A[m,k] * Bt[k, n0+n]   (Bt row-major (K x N))
// ---------------------------------------------------------------------------
__device__ __forceinline__ void mmT64(
    const float* __restrict__ A, const float* __restrict__ Bt,
    int m0, int n0, u16* lA, u16* lB, f32x4_t* acc)
{
    const int t = threadIdx.x;
    const int arow = t >> 2, akq = t & 3;          // A staging
    const int bkrow = t >> 3, bnq = t & 7;         // B staging (transposed)
    const int l = t & 63, w = t >> 6;

    for (int ks = 0; ks < 24; ++ks) {
        const float* pa = A + (size_t)(m0 + arow) * 768 + ks * 32 + akq * 8;
        float4 xa = *reinterpret_cast<const float4*>(pa);
        float4 ya = *reinterpret_cast<const float4*>(pa + 4);
        const float* pb = Bt + (size_t)(ks * 32 + bkrow) * 768 + n0 + bnq * 8;
        float4 xb = *reinterpret_cast<const float4*>(pb);
        float4 yb = *reinterpret_cast<const float4*>(pb + 4);
        __syncthreads();
        s16x8 va;
        va[0]=cvt_bf16(xa.x); va[1]=cvt_bf16(xa.y); va[2]=cvt_bf16(xa.z); va[3]=cvt_bf16(xa.w);
        va[4]=cvt_bf16(ya.x); va[5]=cvt_bf16(ya.y); va[6]=cvt_bf16(ya.z); va[7]=cvt_bf16(ya.w);
        *reinterpret_cast<s16x8*>(lA + (akq * 64 + arow) * 8) = va;
        u16 vb[8];
        vb[0]=cvt_bf16(xb.x); vb[1]=cvt_bf16(xb.y); vb[2]=cvt_bf16(xb.z); vb[3]=cvt_bf16(xb.w);
        vb[4]=cvt_bf16(yb.x); vb[5]=cvt_bf16(yb.y); vb[6]=cvt_bf16(yb.z); vb[7]=cvt_bf16(yb.w);
        const int kb = bkrow >> 3, j = bkrow & 7;
        #pragma unroll
        for (int i = 0; i < 8; ++i)
            lB[(kb * 64 + bnq * 8 + i) * 8 + j] = vb[i];
        __syncthreads();
        const int kk = l >> 4;
        s16x8 af = *reinterpret_cast<const s16x8*>(lA + (kk * 64 + w * 16 + (l & 15)) * 8);
        #pragma unroll
        for (int nb = 0; nb < 4; ++nb) {
            s16x8 bf = *reinterpret_cast<const s16x8*>(lB + (kk * 64 + nb * 16 + (l & 15)) * 8);
            acc[nb] = __builtin_amdgcn_mfma_f32_16x16x32_bf16(af, bf, acc[nb], 0, 0, 0);
        }
    }
}

// ---------------------------------------------------------------------------
// L1 prep (2114 blocks): bf16 conversions + fused q-weights/biases + gate vecs
// ---------------------------------------------------------------------------
__global__ __launch_bounds__(256) void prep_kernel(
    const float* __restrict__ mem, const float* __restrict__ cs,
    const float* __restrict__ ipw, const float* __restrict__ ipb,
    const float* __restrict__ rw, const float* __restrict__ rb,
    const float* __restrict__ www, const float* __restrict__ ww_b,
    const float* __restrict__ ew, const float* __restrict__ outw,
    const float* __restrict__ outb,
    const float* __restrict__ ugw, const float* __restrict__ ugb,
    const float* __restrict__ fgw, const float* __restrict__ fgb,
    u16* __restrict__ memb, u16* __restrict__ csb, u16* __restrict__ ipwb,
    u16* __restrict__ ewb, u16* __restrict__ outwb,
    u16* __restrict__ Wqr, u16* __restrict__ Wqw,
    float* __restrict__ bqr, float* __restrict__ bqw,
    float* __restrict__ vg, float* __restrict__ gc)   // vg: [2][768], gc: [2]
{
    __shared__ u16 lA[2048], lB[2048];
    __shared__ float sred[256];
    const int bid = blockIdx.x, t = threadIdx.x;

    if (bid < 1440) {                       // plain f32 -> bf16 conversion
        const float* src; u16* dst; int base;
        if      (bid < 192)  { src = mem;            dst = memb;  base = bid; }
        else if (bid < 288)  { src = cs;             dst = csb;   base = bid - 192; }
        else if (bid < 864)  { src = ipw + 589824;   dst = ipwb;  base = bid - 288; }  // wk||wv
        else if (bid < 1152) { src = ew;             dst = ewb;   base = bid - 864; }
        else                 { src = outw;           dst = outwb; base = bid - 1152; }
        const size_t i = ((size_t)base * 256 + t) * 8;
        float4 x = *reinterpret_cast<const float4*>(src + i);
        float4 y = *reinterpret_cast<const float4*>(src + i + 4);
        s16x8 o;
        o[0]=cvt_bf16(x.x); o[1]=cvt_bf16(x.y); o[2]=cvt_bf16(x.z); o[3]=cvt_bf16(x.w);
        o[4]=cvt_bf16(y.x); o[5]=cvt_bf16(y.y); o[6]=cvt_bf16(y.z); o[7]=cvt_bf16(y.w);
        *reinterpret_cast<s16x8*>(dst + i) = o;
    } else if (bid < 1728) {                // weight fusion: Wqr = wq@rw, Wqw = wq@www
        const int lid = bid - 1440;
        const int tgt = lid / 144, r = lid % 144;
        const int mt = r / 12, nt = r % 12;
        f32x4_t acc[4] = ACC_INIT;
        mmT64(ipw, tgt == 0 ? rw : www, mt * 64, nt * 64, lA, lB, acc);
        epilogue_bf16(acc, tgt == 0 ? Wqr : Wqw, 768, mt * 64, nt * 64, nullptr, 4);
    } else if (bid < 2112) {                // fused biases: bqX[j] = wq[j,:].dot(bias_in) + bq[j]
        const int lid = bid - 1728;
        const int vec = lid / 192, rr = lid % 192;
        const int w = t >> 6, l = t & 63;
        const int j = rr * 4 + w;
        const float* dv = vec == 0 ? rb : ww_b;
        const float* wqr_ = ipw + (size_t)j * 768 + l * 12;
        float s = 0.f;
        #pragma unroll
        for (int c = 0; c < 3; ++c) {
            float4 a = *reinterpret_cast<const float4*>(wqr_ + c * 4);
            float4 b = *reinterpret_cast<const float4*>(dv + l * 12 + c * 4);
            s += a.x * b.x + a.y * b.y + a.z * b.z + a.w * b.w;
        }
        #pragma unroll
        for (int off = 32; off > 0; off >>= 1) s += __shfl_xor(s, off);
        if (l == 0) (vec == 0 ? bqr : bqw)[j] = s + ipb[j];
    } else {                                // gate vectors: vg[v][k] = sum_j outw[j,k]*gw[768+j]
        const int v = bid - 2112;           // 0: ug, 1: fg
        const float* gw = v == 0 ? ugw : fgw;
        float a0 = 0.f, a1 = 0.f, a2 = 0.f;
        for (int j = 0; j < 768; ++j) {
            const float s = gw[768 + j];
            const float* row = outw + (size_t)j * 768;
            a0 += row[t] * s; a1 += row[t + 256] * s; a2 += row[t + 512] * s;
        }
        vg[v * 768 + t] = a0; vg[v * 768 + t + 256] = a1; vg[v * 768 + t + 512] = a2;
        float cpart = outb[t] * gw[768 + t] + outb[t + 256] * gw[768 + t + 256]
                    + outb[t + 512] * gw[768 + t + 512];
        sred[t] = cpart; __syncthreads();
        #pragma unroll
        for (int off = 128; off > 0; off >>= 1) {
            if (t < off) sred[t] += sred[t + off];
            __syncthreads();
        }
        if (t == 0) gc[v] = sred[0] + (v == 0 ? ugb[0] : fgb[0]);
    }
}

// ---------------------------------------------------------------------------
// L2 proj (336 blocks): kh + vhT, qr, qw, erase
// ---------------------------------------------------------------------------
__global__ __launch_bounds__(256) void proj_kernel(
    const u16* __restrict__ memb, const u16* __restrict__ csb,
    const u16* __restrict__ ipwb, const float* __restrict__ ipb,
    const u16* __restrict__ Wqr, const float* __restrict__ bqr,
    const u16* __restrict__ Wqw, const float* __restrict__ bqw,
    const u16* __restrict__ ewb, const float* __restrict__ eb,
    u16* __restrict__ khb, u16* __restrict__ vhT,
    u16* __restrict__ qrwb, float* __restrict__ erase)
{
    __shared__ u16 lA[8192], lB[8192];
    f32x4_t acc[4] = ACC_INIT;
    const int bid = blockIdx.x;
    if (bid < 192) {
        const int mt = bid / 24, nt = bid % 24;
        mm64b<64>(memb + (size_t)mt * 64 * 768, 768,
                  ipwb + (size_t)nt * 64 * 768, 768, 12, 63, lA, lB, acc, 4);
        const int t = threadIdx.x, l = t & 63, w = t >> 6;
        const int mbase = mt * 64 + w * 16 + (l >> 4) * 4;
        if (nt < 12) {
            #pragma unroll
            for (int nb = 0; nb < 4; ++nb) {
                const int col = nt * 64 + nb * 16 + (l & 15);
                const float bv = ipb[768 + col];
                #pragma unroll
                for (int r = 0; r < 4; ++r)
                    khb[(size_t)(mbase + r) * 768 + col] = cvt_bf16(acc[nb][r] + bv);
            }
        } else {
            #pragma unroll
            for (int nb = 0; nb < 4; ++nb) {
                const int cg = (nt - 12) * 64 + nb * 16 + (l & 15);   // 0..767
                const int h = cg / 96, d = cg % 96;
                const float bv = ipb[1536 + cg];
                u16* dst = vhT + ((size_t)h * 96 + d) * 512;
                #pragma unroll
                for (int r = 0; r < 4; ++r)
                    dst[mbase + r] = cvt_bf16(acc[nb][r] + bv);
            }
        }
    } else if (bid < 240) {
        const int lid = bid - 192, mt = lid / 12, nt = lid % 12;
        mm64b<64>(csb + (size_t)mt * 64 * 768, 768, Wqr + (size_t)nt * 64 * 768, 768,
                  12, 63, lA, lB, acc, 4);
        epilogue_bf16(acc, qrwb, 768, mt * 64, nt * 64, bqr, 4);
    } else if (bid < 288) {
        const int lid = bid - 240, mt = lid / 12, nt = lid % 12;
        mm64b<64>(csb + (size_t)mt * 64 * 768, 768, Wqw + (size_t)nt * 64 * 768, 768,
                  12, 63, lA, lB, acc, 4);
        epilogue_bf16(acc, qrwb + (size_t)256 * 768, 768, mt * 64, nt * 64, bqw, 4);
    } else {
        const int lid = bid - 288, mt = lid / 12, nt = lid % 12;
        mm64b<64>(csb + (size_t)mt * 64 * 768, 768, ewb + (size_t)nt * 64 * 768, 768,
                  12, 63, lA, lB, acc, 4);
        epilogue_f32(acc, erase, 768, mt * 64, nt * 64, eb, 1, 4);
    }
}

// ---------------------------------------------------------------------------
// L3 scores+softmax fused (grid (qt=8, h=8)): K_h + Q-tile in LDS.
// Single-pass (scores std~0.1, clamp at 30 makes overflow impossible):
//   E[h][q][m] = exp(min(s*scale,30)) bf16, linv[h][q] = 1/sum_m.
// ---------------------------------------------------------------------------
__global__ __launch_bounds__(256) void scores_sm_kernel(
    const u16* __restrict__ qrwb, const u16* __restrict__ khb,
    u16* __restrict__ E, float* __restrict__ linv)
{
    __shared__ u16 Kl[512 * 104];     // 106.5 KB
    __shared__ u16 Ql[64 * 104];      // 13.3 KB
    __shared__ float lred[256];

    const int qt = blockIdx.x, h = blockIdx.y, t = threadIdx.x;
    const int l = t & 63, w = t >> 6;

    for (int c = t; c < 512 * 12; c += 256) {
        const int m = c / 12, dc = c % 12;
        s16x8 v = *reinterpret_cast<const s16x8*>(khb + (size_t)m * 768 + h * 96 + dc * 8);
        *reinterpret_cast<s16x8*>(Kl + m * 104 + dc * 8) = v;
    }
    for (int c = t; c < 64 * 12; c += 256) {
        const int q = c / 12, dc = c % 12;
        s16x8 v = *reinterpret_cast<const s16x8*>(qrwb + (size_t)(qt * 64 + q) * 768 + h * 96 + dc * 8);
        *reinterpret_cast<s16x8*>(Ql + q * 104 + dc * 8) = v;
    }
    __syncthreads();

    float l_acc[4] = {0.f, 0.f, 0.f, 0.f};

    for (int mt = 0; mt < 8; ++mt) {
        f32x4_t acc[4] = ACC_INIT;
        #pragma unroll
        for (int ks = 0; ks < 3; ++ks) {
            s16x8 af = *reinterpret_cast<const s16x8*>(
                Kl + (mt * 64 + w * 16 + (l & 15)) * 104 + ks * 32 + (l >> 4) * 8);
            #pragma unroll
            for (int nb = 0; nb < 4; ++nb) {
                s16x8 bf = *reinterpret_cast<const s16x8*>(
                    Ql + (nb * 16 + (l & 15)) * 104 + ks * 32 + (l >> 4) * 8);
                acc[nb] = __builtin_amdgcn_mfma_f32_16x16x32_bf16(af, bf, acc[nb], 0, 0, 0);
            }
        }
        const int mbase = mt * 64 + w * 16 + (l >> 4) * 4;
        #pragma unroll
        for (int nb = 0; nb < 4; ++nb) {
            const int q = qt * 64 + nb * 16 + (l & 15);
            s16x4 pk;
            float e0 = expf(fminf(acc[nb][0] * SCALE_, 30.0f));
            float e1 = expf(fminf(acc[nb][1] * SCALE_, 30.0f));
            float e2 = expf(fminf(acc[nb][2] * SCALE_, 30.0f));
            float e3 = expf(fminf(acc[nb][3] * SCALE_, 30.0f));
            l_acc[nb] += (e0 + e1) + (e2 + e3);
            pk[0] = cvt_bf16(e0); pk[1] = cvt_bf16(e1);
            pk[2] = cvt_bf16(e2); pk[3] = cvt_bf16(e3);
            *reinterpret_cast<s16x4*>(E + ((size_t)h * 512 + q) * 512 + mbase) = pk;
        }
    }

    #pragma unroll
    for (int nb = 0; nb < 4; ++nb) {
        float v = l_acc[nb];
        v += __shfl_xor(v, 16);
        v += __shfl_xor(v, 32);
        if (l < 16) lred[w * 64 + nb * 16 + l] = v;
    }
    __syncthreads();
    if (t < 64) {
        const float s = lred[t] + lred[64 + t] + lred[128 + t] + lred[192 + t];
        linv[h * 512 + qt * 64 + t] = 1.0f / s;
    }
}

// ---------------------------------------------------------------------------
// L4 PV (grid (4,2,8)): ctx = linv * (E_read @ vhT^T) -> ctxb bf16
// ---------------------------------------------------------------------------
__global__ __launch_bounds__(256) void pv_kernel(
    const u16* __restrict__ E, const float* __restrict__ linv,
    const u16* __restrict__ vhT, u16* __restrict__ ctxb)
{
    __shared__ u16 lA[8192], lB[8192];
    f32x4_t acc[4] = ACC_INIT;
    const int h = blockIdx.z, mt = blockIdx.x, nt = blockIdx.y;
    const int n0 = nt * 64;
    const int nfrag = nt == 0 ? 4 : 2;
    const int bclamp = nt == 0 ? 63 : 31;
    mm64b<64>(E + ((size_t)h * 512 + mt * 64) * 512, 512,
              vhT + ((size_t)h * 96 + n0) * 512, 512, 8, bclamp, lA, lB, acc, nfrag);
    const int t = threadIdx.x, l = t & 63, w = t >> 6;
    const int mbase = mt * 64 + w * 16 + (l >> 4) * 4;
    #pragma unroll
    for (int nb = 0; nb < 4; ++nb) {
        if (nb >= nfrag) break;
        const int col = n0 + nb * 16 + (l & 15);
        #pragma unroll
        for (int r = 0; r < 4; ++r) {
            const float lv = linv[h * 512 + mbase + r];
            ctxb[(size_t)(mbase + r) * 768 + h * 96 + col] = cvt_bf16(acc[nb][r] * lv);
        }
    }
}

// ---------------------------------------------------------------------------
// L5 finalize (816 blocks): [0,48) outproj; [48,304) gates+delta; [304,816) ww
// ---------------------------------------------------------------------------
__global__ __launch_bounds__(256) void finalize_kernel(
    const u16* __restrict__ ctxb, const u16* __restrict__ outwb,
    const float* __restrict__ outb, float* __restrict__ rd_out,
    const float* __restrict__ cs, const float* __restrict__ wdta,
    const float* __restrict__ erase,
    const float* __restrict__ ugw, const float* __restrict__ fgw,
    const float* __restrict__ vg, const float* __restrict__ gc,
    const u16* __restrict__ E, const float* __restrict__ linv,
    float* __restrict__ delta, float* __restrict__ wwb)
{
    __shared__ u16 lA[8192], lB[8192];
    const int bid = blockIdx.x, t = threadIdx.x;
    if (bid < 48) {
        f32x4_t acc[4] = ACC_INIT;
        const int mt = bid / 12, nt = bid % 12;
        mm64b<64>(ctxb + (size_t)mt * 64 * 768, 768, outwb + (size_t)nt * 64 * 768, 768,
                  12, 63, lA, lB, acc, 4);
        epilogue_f32(acc, rd_out, 768, mt * 64, nt * 64, outb, 0, 4);
    } else if (bid < 304) {
        const int b = bid - 48;
        __shared__ float red[8];
        float pu = 0.f, pf = 0.f;
        #pragma unroll
        for (int c = 0; c < 3; ++c) {
            const int i = t + c * 256;
            const float cv = cs[(size_t)b * 768 + i];
            const float xv = bf16_f32(ctxb[(size_t)b * 768 + i]);
            pu += cv * ugw[i] + xv * vg[i];
            pf += cv * fgw[i] + xv * vg[768 + i];
        }
        const int w = t >> 6, l = t & 63;
        #pragma unroll
        for (int off = 32; off > 0; off >>= 1) {
            pu += __shfl_xor(pu, off);
            pf += __shfl_xor(pf, off);
        }
        if (l == 0) { red[w] = pu; red[4 + w] = pf; }
        __syncthreads();
        const float ug = 1.0f / (1.0f + expf(-(red[0] + red[1] + red[2] + red[3] + gc[0])));
        const float fg = 1.0f / (1.0f + expf(-(red[4] + red[5] + red[6] + red[7] + gc[1])));
        #pragma unroll
        for (int c = 0; c < 3; ++c) {
            const int i = t + c * 256;
            delta[(size_t)b * 768 + i] = wdta[(size_t)b * 768 + i] * ug
                                       - erase[(size_t)b * 768 + i] * fg;
        }
    } else {
        const int idx = (bid - 304) * 256 + t;
        const int b = idx >> 9, m = idx & 511;
        float s = 0.f;
        #pragma unroll
        for (int h = 0; h < H_; ++h)
            s += bf16_f32(E[((size_t)h * 512 + 256 + b) * 512 + m]) * linv[h * 512 + 256 + b];
        wwb[(size_t)b * 512 + m] = s * 0.125f;
    }
}

// ---------------------------------------------------------------------------
// L6 memory update (403 MB writer): out = mem + ww*delta, NT stores. Runs last.
// ---------------------------------------------------------------------------
__global__ __launch_bounds__(192) void update_mem(
    const float* __restrict__ mem, const float* __restrict__ ww,
    const float* __restrict__ delta, float* __restrict__ out)
{
    const int blk = blockIdx.x;
    const int b   = blk >> 6;
    const int m0  = (blk & 63) << 3;
    const int t   = threadIdx.x;

    const f32x4_t d4 = *reinterpret_cast<const f32x4_t*>(delta + (size_t)b * D_ + t * 4);
    const f32x4_t* m4 = reinterpret_cast<const f32x4_t*>(mem);
    f32x4_t* o4 = reinterpret_cast<f32x4_t*>(out + (size_t)b * M_ * D_);

    #pragma unroll
    for (int i = 0; i < 8; ++i) {
        const int m = m0 + i;
        const float w = ww[(size_t)b * M_ + m];
        f32x4_t mm = m4[(size_t)m * 192 + t];
        f32x4_t r = mm + w * d4;
        __builtin_nontemporal_store(r, &o4[(size_t)m * 192 + t]);
    }
}

// ---------------------------------------------------------------------------
extern "C" void kernel_launch(void* const* d_in, const int* in_sizes, int n_in,
                              void* d_out, int out_size, void* d_ws, size_t ws_size,
                              hipStream_t stream)
{
    const float* cs   = (const float*)d_in[0];
    const float* wdta = (const float*)d_in[1];
    const float* mem  = (const float*)d_in[2];
    const float* ipw  = (const float*)d_in[3];
    const float* ipb  = (const float*)d_in[4];
    const float* outw = (const float*)d_in[5];
    const float* outb = (const float*)d_in[6];
    const float* rw   = (const float*)d_in[7];
    const float* rb   = (const float*)d_in[8];
    const float* ww_w = (const float*)d_in[9];
    const float* ww_b = (const float*)d_in[10];
    const float* ew   = (const float*)d_in[11];
    const float* eb   = (const float*)d_in[12];
    const float* ugw  = (const float*)d_in[13];
    const float* ugb  = (const float*)d_in[14];
    const float* fgw  = (const float*)d_in[15];
    const float* fgb  = (const float*)d_in[16];

    float* rd_out  = (float*)d_out;              // read_data (B, D)
    float* mem_out = (float*)d_out + B_ * D_;    // updated_memory (B, M, D)

    // Scratch in mem_out region (dead until update_mem; update_mem reads only
    // inputs + d_ws). Offsets in f32 WORDS; size = u16_elems/2 for bf16 bufs.
    //   memb  512*768  bf16 -> 196608 f   @ 0
    //   csb   256*768  bf16 ->  98304 f   @ 196608
    //   ipwb 1536*768  bf16 -> 589824 f   @ 294912
    //   ewb   768*768  bf16 -> 294912 f   @ 884736
    //   outwb 768*768  bf16 -> 294912 f   @ 1179648
    //   Wqr   768*768  bf16 -> 294912 f   @ 1474560
    //   Wqw   768*768  bf16 -> 294912 f   @ 1769472
    //   bqr   768 f                       @ 2064384
    //   bqw   768 f                       @ 2065152
    //   khb   512*768  bf16 -> 196608 f   @ 2065920
    //   vhT   768*512  bf16 -> 196608 f   @ 2262528
    //   qrwb  512*768  bf16 -> 196608 f   @ 2459136   (end 2655744 f = 10.6 MB)
    float* S0 = mem_out;
    u16*   memb  = (u16*)(S0 + 0);
    u16*   csb   = (u16*)(S0 + 196608);
    u16*   ipwb  = (u16*)(S0 + 294912);
    u16*   ewb   = (u16*)(S0 + 884736);
    u16*   outwb = (u16*)(S0 + 1179648);
    u16*   Wqr   = (u16*)(S0 + 1474560);
    u16*   Wqw   = (u16*)(S0 + 1769472);
    float* bqr   =        S0 + 2064384;
    float* bqw   =        S0 + 2065152;
    u16*   khb   = (u16*)(S0 + 2065920);
    u16*   vhT   = (u16*)(S0 + 2262528);
    u16*   qrwb  = (u16*)(S0 + 2459136);

    // d_ws (f32 words; every offset %4==0 for 16B vector alignment):
    //   erase 196608 @ 0; ctxb (256*768 bf16) 98304 @ 196608;
    //   E (8*512*512 bf16) 1048576 @ 294912; linv 4096 @ 1343488;
    //   vg 1536 @ 1347584; gc 16 @ 1349120; delta 196608 @ 1349136;
    //   wwb 131072 @ 1545744  (end 1676816 f = 6.7 MB)
    float* ws    = (float*)d_ws;
    float* erase = ws;
    u16*   ctxb  = (u16*)(ws + 196608);
    u16*   E     = (u16*)(ws + 294912);
    float* linv  =        ws + 1343488;
    float* vg    =        ws + 1347584;
    float* gc    =        ws + 1349120;
    float* delta =        ws + 1349136;
    float* wwb   =        ws + 1545744;

    prep_kernel<<<2114, 256, 0, stream>>>(mem, cs, ipw, ipb, rw, rb, ww_w, ww_b,
                                          ew, outw, outb, ugw, ugb, fgw, fgb,
                                          memb, csb, ipwb, ewb, outwb,
                                          Wqr, Wqw, bqr, bqw, vg, gc);
    proj_kernel<<<336, 256, 0, stream>>>(memb, csb, ipwb, ipb, Wqr, bqr, Wqw, bqw,
                                         ewb, eb, khb, vhT, qrwb, erase);
    scores_sm_kernel<<<dim3(8, 8), 256, 0, stream>>>(qrwb, khb, E, linv);
    pv_kernel<<<dim3(4, 2, 8), 256, 0, stream>>>(E, linv, vhT, ctxb);
    finalize_kernel<<<816, 256, 0, stream>>>(ctxb, outwb, outb, rd_out,
                                             cs, wdta, erase, ugw, fgw, vg, gc,
                                             E, linv, delta, wwb);
    update_mem<<<B_ * (M_ / 8), 192, 0, stream>>>(mem, wwb, delta, mem_out);
}

// Round 8
// 161.093 us; speedup vs baseline: 1.0772x; 1.0772x over previous
//
#include <hip/hip_runtime.h>
#include <math.h>

// Problem constants
#define B_ 256
#define M_ 512
#define D_ 768
#define H_ 8
#define DH_ 96
#define C_ 768

typedef float  f32x4_t __attribute__((ext_vector_type(4)));
typedef short  s16x8   __attribute__((ext_vector_type(8)));
typedef short  s16x4   __attribute__((ext_vector_type(4)));
typedef unsigned short u16;

__device__ __forceinline__ u16 cvt_bf16(float f) {
    union { float f; unsigned int u; } v; v.f = f;
    unsigned int r = (v.u + 0x7FFFu + ((v.u >> 16) & 1u)) >> 16;
    return (u16)r;
}
__device__ __forceinline__ float bf16_f32(u16 h) {
    union { unsigned int u; float f; } v; v.u = ((unsigned int)h) << 16;
    return v.f;
}

#define ACC_INIT {{0,0,0,0},{0,0,0,0},{0,0,0,0},{0,0,0,0}}
#define SCALE_ 0.10206207261596577f   // 1/sqrt(96)

// ---------------------------------------------------------------------------
// 64x64 bf16 MFMA GEMM core (proven R5): tile = A(64xK) @ B(64xK)^T.
// ---------------------------------------------------------------------------
template<int BK>
__device__ __forceinline__ void mm64b(
    const u16* __restrict__ A, int lda, const u16* __restrict__ B, int ldb,
    int ksteps, int bRowClamp, u16* lA, u16* lB, f32x4_t* acc, int nfrag)
{
    constexpr int NL = BK / 32;
    const int t = threadIdx.x;
    const int srow = t >> 2, kq = t & 3;
    const int l = t & 63, w = t >> 6;
    const int brow = srow < bRowClamp ? srow : bRowClamp;

    for (int ks = 0; ks < ksteps; ++ks) {
        s16x8 va[NL], vb[NL];
        #pragma unroll
        for (int c = 0; c < NL; ++c) {
            const int ko = ks * BK + (kq * NL + c) * 8;
            va[c] = *reinterpret_cast<const s16x8*>(A + (size_t)srow * lda + ko);
            vb[c] = *reinterpret_cast<const s16x8*>(B + (size_t)brow * ldb + ko);
        }
        __syncthreads();
        #pragma unroll
        for (int c = 0; c < NL; ++c) {
            const int kb = kq * NL + c;
            *reinterpret_cast<s16x8*>(lA + (kb * 64 + srow) * 8) = va[c];
            *reinterpret_cast<s16x8*>(lB + (kb * 64 + srow) * 8) = vb[c];
        }
        __syncthreads();
        #pragma unroll
        for (int ksub = 0; ksub < NL; ++ksub) {
            const int kb = (l >> 4) + ksub * 4;
            s16x8 af = *reinterpret_cast<const s16x8*>(lA + (kb * 64 + w * 16 + (l & 15)) * 8);
            #pragma unroll
            for (int nb = 0; nb < 4; ++nb) {
                if (nb < nfrag) {
                    s16x8 bf = *reinterpret_cast<const s16x8*>(lB + (kb * 64 + nb * 16 + (l & 15)) * 8);
                    acc[nb] = __builtin_amdgcn_mfma_f32_16x16x32_bf16(af, bf, acc[nb], 0, 0, 0);
                }
            }
        }
    }
}

// C/D layout: col = lane&15, row = (lane>>4)*4 + reg (within wave's 16-row slice).
__device__ __forceinline__ void epilogue_f32(
    const f32x4_t* acc, float* out, int ldo, int m0, int n0,
    const float* bias, int act, int nfrag)
{
    const int t = threadIdx.x, l = t & 63, w = t >> 6;
    const int mbase = m0 + w * 16 + (l >> 4) * 4;
    #pragma unroll
    for (int nb = 0; nb < 4; ++nb) {
        if (nb >= nfrag) break;
        const int col = n0 + nb * 16 + (l & 15);
        const float bv = bias ? bias[col] : 0.0f;
        #pragma unroll
        for (int r = 0; r < 4; ++r) {
            float v = acc[nb][r] + bv;
            if (act) v = 1.0f / (1.0f + expf(-v));
            out[(size_t)(mbase + r) * ldo + col] = v;
        }
    }
}

__device__ __forceinline__ void epilogue_bf16(
    const f32x4_t* acc, u16* out, int ldo, int m0, int n0,
    const float* bias, int nfrag)
{
    const int t = threadIdx.x, l = t & 63, w = t >> 6;
    const int mbase = m0 + w * 16 + (l >> 4) * 4;
    #pragma unroll
    for (int nb = 0; nb < 4; ++nb) {
        if (nb >= nfrag) break;
        const int col = n0 + nb * 16 + (l & 15);
        const float bv = bias ? bias[col] : 0.0f;
        #pragma unroll
        for (int r = 0; r < 4; ++r)
            out[(size_t)(mbase + r) * ldo + col] = cvt_bf16(acc[nb][r] + bv);
    }
}

// ---------------------------------------------------------------------------
// L1 conv (2328 blocks): f32->bf16 conversions (2304) + vg/gc GEMV (24).
// vg[v][k] = sum_d outw[d][k]*gw[768+d];  gc[v] = outb.gw_d + gb.
// ---------------------------------------------------------------------------
__global__ __launch_bounds__(256) void conv_kernel(
    const float* __restrict__ mem, const float* __restrict__ cs,
    const float* __restrict__ ipw, const float* __restrict__ rw,
    const float* __restrict__ www, const float* __restrict__ ew,
    const float* __restrict__ outw, const float* __restrict__ outb,
    const float* __restrict__ ugw, const float* __restrict__ ugb,
    const float* __restrict__ fgw, const float* __restrict__ fgb,
    u16* __restrict__ memb, u16* __restrict__ csb, u16* __restrict__ ipwb,
    u16* __restrict__ rwb, u16* __restrict__ wwwb, u16* __restrict__ ewb,
    u16* __restrict__ outwb, float* __restrict__ vg, float* __restrict__ gc)
{
    __shared__ float sred[256];
    const int bid = blockIdx.x, t = threadIdx.x;

    if (bid < 2304) {                       // plain f32 -> bf16 conversion
        const float* src; u16* dst; int base;
        if      (bid < 192)  { src = mem;  dst = memb;  base = bid; }
        else if (bid < 288)  { src = cs;   dst = csb;   base = bid - 192; }
        else if (bid < 1152) { src = ipw;  dst = ipwb;  base = bid - 288; }   // wq|wk|wv
        else if (bid < 1440) { src = rw;   dst = rwb;   base = bid - 1152; }
        else if (bid < 1728) { src = www;  dst = wwwb;  base = bid - 1440; }
        else if (bid < 2016) { src = ew;   dst = ewb;   base = bid - 1728; }
        else                 { src = outw; dst = outwb; base = bid - 2016; }
        const size_t i = ((size_t)base * 256 + t) * 8;
        float4 x = *reinterpret_cast<const float4*>(src + i);
        float4 y = *reinterpret_cast<const float4*>(src + i + 4);
        s16x8 o;
        o[0]=cvt_bf16(x.x); o[1]=cvt_bf16(x.y); o[2]=cvt_bf16(x.z); o[3]=cvt_bf16(x.w);
        o[4]=cvt_bf16(y.x); o[5]=cvt_bf16(y.y); o[6]=cvt_bf16(y.z); o[7]=cvt_bf16(y.w);
        *reinterpret_cast<s16x8*>(dst + i) = o;
    } else {                                // vg GEMV: 24 blocks (2 v x 12 kt)
        const int lid = bid - 2304;
        const int v = lid / 12, kt = lid % 12;
        const float* gw = v == 0 ? ugw : fgw;
        const int c = t & 63, g = t >> 6;
        const int col = kt * 64 + c;
        float acc = 0.f;
        #pragma unroll 4
        for (int i = 0; i < 192; ++i) {
            const int row = g * 192 + i;
            acc += outw[(size_t)row * 768 + col] * gw[768 + row];
        }
        sred[t] = acc;
        __syncthreads();
        if (g == 0)
            vg[v * 768 + col] = sred[c] + sred[64 + c] + sred[128 + c] + sred[192 + c];
        if (kt == 0) {                      // gc in one block per v
            __syncthreads();
            float cp = outb[t] * gw[768 + t] + outb[t + 256] * gw[768 + t + 256]
                     + outb[t + 512] * gw[768 + t + 512];
            sred[t] = cp; __syncthreads();
            #pragma unroll
            for (int off = 128; off > 0; off >>= 1) {
                if (t < off) sred[t] += sred[t + off];
                __syncthreads();
            }
            if (t == 0) gc[v] = sred[0] + (v == 0 ? ugb[0] : fgb[0]);
        }
    }
}

// ---------------------------------------------------------------------------
// L2 stage1 (336 blocks): kh+vhT (192), read keys (48), write keys (48), erase (48)
// ---------------------------------------------------------------------------
__global__ __launch_bounds__(256) void stage1_kernel(
    const u16* __restrict__ memb, const u16* __restrict__ csb,
    const u16* __restrict__ ipwb, const float* __restrict__ ipb,
    const u16* __restrict__ rwb, const float* __restrict__ rb,
    const u16* __restrict__ wwwb, const float* __restrict__ ww_b,
    const u16* __restrict__ ewb, const float* __restrict__ eb,
    u16* __restrict__ khb, u16* __restrict__ vhT,
    u16* __restrict__ rwkeysb, float* __restrict__ erase)
{
    __shared__ u16 lA[8192], lB[8192];
    f32x4_t acc[4] = ACC_INIT;
    const int bid = blockIdx.x;
    if (bid < 192) {
        const int mt = bid / 24, nt = bid % 24;
        mm64b<64>(memb + (size_t)mt * 64 * 768, 768,
                  ipwb + (size_t)768 * 768 + (size_t)nt * 64 * 768, 768,  // wk|wv rows
                  12, 63, lA, lB, acc, 4);
        const int t = threadIdx.x, l = t & 63, w = t >> 6;
        const int mbase = mt * 64 + w * 16 + (l >> 4) * 4;
        if (nt < 12) {
            #pragma unroll
            for (int nb = 0; nb < 4; ++nb) {
                const int col = nt * 64 + nb * 16 + (l & 15);
                const float bv = ipb[768 + col];
                #pragma unroll
                for (int r = 0; r < 4; ++r)
                    khb[(size_t)(mbase + r) * 768 + col] = cvt_bf16(acc[nb][r] + bv);
            }
        } else {
            #pragma unroll
            for (int nb = 0; nb < 4; ++nb) {
                const int cg = (nt - 12) * 64 + nb * 16 + (l & 15);   // 0..767
                const int h = cg / 96, d = cg % 96;
                const float bv = ipb[1536 + cg];
                u16* dst = vhT + ((size_t)h * 96 + d) * 512;
                #pragma unroll
                for (int r = 0; r < 4; ++r)
                    dst[mbase + r] = cvt_bf16(acc[nb][r] + bv);
            }
        }
    } else if (bid < 240) {
        const int lid = bid - 192, mt = lid / 12, nt = lid % 12;
        mm64b<64>(csb + (size_t)mt * 64 * 768, 768, rwb + (size_t)nt * 64 * 768, 768,
                  12, 63, lA, lB, acc, 4);
        epilogue_bf16(acc, rwkeysb, 768, mt * 64, nt * 64, rb, 4);
    } else if (bid < 288) {
        const int lid = bid - 240, mt = lid / 12, nt = lid % 12;
        mm64b<64>(csb + (size_t)mt * 64 * 768, 768, wwwb + (size_t)nt * 64 * 768, 768,
                  12, 63, lA, lB, acc, 4);
        epilogue_bf16(acc, rwkeysb + (size_t)256 * 768, 768, mt * 64, nt * 64, ww_b, 4);
    } else {
        const int lid = bid - 288, mt = lid / 12, nt = lid % 12;
        mm64b<64>(csb + (size_t)mt * 64 * 768, 768, ewb + (size_t)nt * 64 * 768, 768,
                  12, 63, lA, lB, acc, 4);
        epilogue_f32(acc, erase, 768, mt * 64, nt * 64, eb, 1, 4);
    }
}

// ---------------------------------------------------------------------------
// L3 stage2 (96 blocks): qrw = rwkeys(512x768) @ wq^T + bq -> bf16
// ---------------------------------------------------------------------------
__global__ __launch_bounds__(256) void stage2_kernel(
    const u16* __restrict__ rwkeysb, const u16* __restrict__ ipwb,
    const float* __restrict__ ipb, u16* __restrict__ qrwb)
{
    __shared__ u16 lA[8192], lB[8192];
    f32x4_t acc[4] = ACC_INIT;
    const int mt = blockIdx.x / 12, nt = blockIdx.x % 12;
    mm64b<64>(rwkeysb + (size_t)mt * 64 * 768, 768, ipwb + (size_t)nt * 64 * 768, 768,
              12, 63, lA, lB, acc, 4);
    epilogue_bf16(acc, qrwb, 768, mt * 64, nt * 64, ipb, 4);
}

// ---------------------------------------------------------------------------
// L4 scores+softmax fused (grid (qt=8, h=8)): K_h + Q-tile in LDS.
// Single-pass, exp-arg clamped at 30 (never binds on valid data):
//   E[h][q][m] = exp(min(s*scale,30)) bf16, linv[h][q] = 1/sum_m.
// ---------------------------------------------------------------------------
__global__ __launch_bounds__(256) void scores_sm_kernel(
    const u16* __restrict__ qrwb, const u16* __restrict__ khb,
    u16* __restrict__ E, float* __restrict__ linv)
{
    __shared__ u16 Kl[512 * 104];     // 106.5 KB
    __shared__ u16 Ql[64 * 104];      // 13.3 KB
    __shared__ float lred[256];

    const int qt = blockIdx.x, h = blockIdx.y, t = threadIdx.x;
    const int l = t & 63, w = t >> 6;

    for (int c = t; c < 512 * 12; c += 256) {
        const int m = c / 12, dc = c % 12;
        s16x8 v = *reinterpret_cast<const s16x8*>(khb + (size_t)m * 768 + h * 96 + dc * 8);
        *reinterpret_cast<s16x8*>(Kl + m * 104 + dc * 8) = v;
    }
    for (int c = t; c < 64 * 12; c += 256) {
        const int q = c / 12, dc = c % 12;
        s16x8 v = *reinterpret_cast<const s16x8*>(qrwb + (size_t)(qt * 64 + q) * 768 + h * 96 + dc * 8);
        *reinterpret_cast<s16x8*>(Ql + q * 104 + dc * 8) = v;
    }
    __syncthreads();

    float l_acc[4] = {0.f, 0.f, 0.f, 0.f};

    for (int mt = 0; mt < 8; ++mt) {
        f32x4_t acc[4] = ACC_INIT;
        #pragma unroll
        for (int ks = 0; ks < 3; ++ks) {
            s16x8 af = *reinterpret_cast<const s16x8*>(
                Kl + (mt * 64 + w * 16 + (l & 15)) * 104 + ks * 32 + (l >> 4) * 8);
            #pragma unroll
            for (int nb = 0; nb < 4; ++nb) {
                s16x8 bf = *reinterpret_cast<const s16x8*>(
                    Ql + (nb * 16 + (l & 15)) * 104 + ks * 32 + (l >> 4) * 8);
                acc[nb] = __builtin_amdgcn_mfma_f32_16x16x32_bf16(af, bf, acc[nb], 0, 0, 0);
            }
        }
        const int mbase = mt * 64 + w * 16 + (l >> 4) * 4;
        #pragma unroll
        for (int nb = 0; nb < 4; ++nb) {
            const int q = qt * 64 + nb * 16 + (l & 15);
            s16x4 pk;
            float e0 = expf(fminf(acc[nb][0] * SCALE_, 30.0f));
            float e1 = expf(fminf(acc[nb][1] * SCALE_, 30.0f));
            float e2 = expf(fminf(acc[nb][2] * SCALE_, 30.0f));
            float e3 = expf(fminf(acc[nb][3] * SCALE_, 30.0f));
            l_acc[nb] += (e0 + e1) + (e2 + e3);
            pk[0] = cvt_bf16(e0); pk[1] = cvt_bf16(e1);
            pk[2] = cvt_bf16(e2); pk[3] = cvt_bf16(e3);
            *reinterpret_cast<s16x4*>(E + ((size_t)h * 512 + q) * 512 + mbase) = pk;
        }
    }

    #pragma unroll
    for (int nb = 0; nb < 4; ++nb) {
        float v = l_acc[nb];
        v += __shfl_xor(v, 16);
        v += __shfl_xor(v, 32);
        if (l < 16) lred[w * 64 + nb * 16 + l] = v;
    }
    __syncthreads();
    if (t < 64) {
        const float s = lred[t] + lred[64 + t] + lred[128 + t] + lred[192 + t];
        linv[h * 512 + qt * 64 + t] = 1.0f / s;
    }
}

// ---------------------------------------------------------------------------
// L5 PV (grid (4,2,8)): ctx = linv * (E_read @ vhT^T) -> ctxb bf16
// ---------------------------------------------------------------------------
__global__ __launch_bounds__(256) void pv_kernel(
    const u16* __restrict__ E, const float* __restrict__ linv,
    const u16* __restrict__ vhT, u16* __restrict__ ctxb)
{
    __shared__ u16 lA[8192], lB[8192];
    f32x4_t acc[4] = ACC_INIT;
    const int h = blockIdx.z, mt = blockIdx.x, nt = blockIdx.y;
    const int n0 = nt * 64;
    const int nfrag = nt == 0 ? 4 : 2;
    const int bclamp = nt == 0 ? 63 : 31;
    mm64b<64>(E + ((size_t)h * 512 + mt * 64) * 512, 512,
              vhT + ((size_t)h * 96 + n0) * 512, 512, 8, bclamp, lA, lB, acc, nfrag);
    const int t = threadIdx.x, l = t & 63, w = t >> 6;
    const int mbase = mt * 64 + w * 16 + (l >> 4) * 4;
    #pragma unroll
    for (int nb = 0; nb < 4; ++nb) {
        if (nb >= nfrag) break;
        const int col = n0 + nb * 16 + (l & 15);
        #pragma unroll
        for (int r = 0; r < 4; ++r) {
            const float lv = linv[h * 512 + mbase + r];
            ctxb[(size_t)(mbase + r) * 768 + h * 96 + col] = cvt_bf16(acc[nb][r] * lv);
        }
    }
}

// ---------------------------------------------------------------------------
// L6 finalize (816 blocks): [0,48) outproj; [48,304) gates+delta; [304,816) ww
// ---------------------------------------------------------------------------
__global__ __launch_bounds__(256) void finalize_kernel(
    const u16* __restrict__ ctxb, const u16* __restrict__ outwb,
    const float* __restrict__ outb, float* __restrict__ rd_out,
    const float* __restrict__ cs, const float* __restrict__ wdta,
    const float* __restrict__ erase,
    const float* __restrict__ ugw, const float* __restrict__ fgw,
    const float* __restrict__ vg, const float* __restrict__ gc,
    const u16* __restrict__ E, const float* __restrict__ linv,
    float* __restrict__ delta, float* __restrict__ wwb)
{
    __shared__ u16 lA[8192], lB[8192];
    const int bid = blockIdx.x, t = threadIdx.x;
    if (bid < 48) {
        f32x4_t acc[4] = ACC_INIT;
        const int mt = bid / 12, nt = bid % 12;
        mm64b<64>(ctxb + (size_t)mt * 64 * 768, 768, outwb + (size_t)nt * 64 * 768, 768,
                  12, 63, lA, lB, acc, 4);
        epilogue_f32(acc, rd_out, 768, mt * 64, nt * 64, outb, 0, 4);
    } else if (bid < 304) {
        const int b = bid - 48;
        __shared__ float red[8];
        float pu = 0.f, pf = 0.f;
        #pragma unroll
        for (int c = 0; c < 3; ++c) {
            const int i = t + c * 256;
            const float cv = cs[(size_t)b * 768 + i];
            const float xv = bf16_f32(ctxb[(size_t)b * 768 + i]);
            pu += cv * ugw[i] + xv * vg[i];
            pf += cv * fgw[i] + xv * vg[768 + i];
        }
        const int w = t >> 6, l = t & 63;
        #pragma unroll
        for (int off = 32; off > 0; off >>= 1) {
            pu += __shfl_xor(pu, off);
            pf += __shfl_xor(pf, off);
        }
        if (l == 0) { red[w] = pu; red[4 + w] = pf; }
        __syncthreads();
        const float ug = 1.0f / (1.0f + expf(-(red[0] + red[1] + red[2] + red[3] + gc[0])));
        const float fg = 1.0f / (1.0f + expf(-(red[4] + red[5] + red[6] + red[7] + gc[1])));
        #pragma unroll
        for (int c = 0; c < 3; ++c) {
            const int i = t + c * 256;
            delta[(size_t)b * 768 + i] = wdta[(size_t)b * 768 + i] * ug
                                       - erase[(size_t)b * 768 + i] * fg;
        }
    } else {
        const int idx = (bid - 304) * 256 + t;
        const int b = idx >> 9, m = idx & 511;
        float s = 0.f;
        #pragma unroll
        for (int h = 0; h < H_; ++h)
            s += bf16_f32(E[((size_t)h * 512 + 256 + b) * 512 + m]) * linv[h * 512 + 256 + b];
        wwb[(size_t)b * 512 + m] = s * 0.125f;
    }
}

// ---------------------------------------------------------------------------
// L7 memory update (403 MB writer): out = mem + ww*delta, NT stores. Runs last.
// ---------------------------------------------------------------------------
__global__ __launch_bounds__(192) void update_mem(
    const float* __restrict__ mem, const float* __restrict__ ww,
    const float* __restrict__ delta, float* __restrict__ out)
{
    const int blk = blockIdx.x;
    const int b   = blk >> 6;
    const int m0  = (blk & 63) << 3;
    const int t   = threadIdx.x;

    const f32x4_t d4 = *reinterpret_cast<const f32x4_t*>(delta + (size_t)b * D_ + t * 4);
    const f32x4_t* m4 = reinterpret_cast<const f32x4_t*>(mem);
    f32x4_t* o4 = reinterpret_cast<f32x4_t*>(out + (size_t)b * M_ * D_);

    #pragma unroll
    for (int i = 0; i < 8; ++i) {
        const int m = m0 + i;
        const float w = ww[(size_t)b * M_ + m];
        f32x4_t mm = m4[(size_t)m * 192 + t];
        f32x4_t r = mm + w * d4;
        __builtin_nontemporal_store(r, &o4[(size_t)m * 192 + t]);
    }
}

// ---------------------------------------------------------------------------
extern "C" void kernel_launch(void* const* d_in, const int* in_sizes, int n_in,
                              void* d_out, int out_size, void* d_ws, size_t ws_size,
                              hipStream_t stream)
{
    const float* cs   = (const float*)d_in[0];
    const float* wdta = (const float*)d_in[1];
    const float* mem  = (const float*)d_in[2];
    const float* ipw  = (const float*)d_in[3];
    const float* ipb  = (const float*)d_in[4];
    const float* outw = (const float*)d_in[5];
    const float* outb = (const float*)d_in[6];
    const float* rw   = (const float*)d_in[7];
    const float* rb   = (const float*)d_in[8];
    const float* ww_w = (const float*)d_in[9];
    const float* ww_b = (const float*)d_in[10];
    const float* ew   = (const float*)d_in[11];
    const float* eb   = (const float*)d_in[12];
    const float* ugw  = (const float*)d_in[13];
    const float* ugb  = (const float*)d_in[14];
    const float* fgw  = (const float*)d_in[15];
    const float* fgb  = (const float*)d_in[16];

    float* rd_out  = (float*)d_out;              // read_data (B, D)
    float* mem_out = (float*)d_out + B_ * D_;    // updated_memory (B, M, D)

    // Scratch in mem_out region (dead until update_mem; update_mem reads only
    // inputs + d_ws). Offsets in f32 WORDS (u16 count / 2), all %4==0:
    //   memb   512*768 bf16 -> 196608 @ 0
    //   csb    256*768 bf16 ->  98304 @ 196608
    //   ipwb  2304*768 bf16 -> 884736 @ 294912
    //   rwb    768*768 bf16 -> 294912 @ 1179648
    //   wwwb   768*768 bf16 -> 294912 @ 1474560
    //   ewb    768*768 bf16 -> 294912 @ 1769472
    //   outwb  768*768 bf16 -> 294912 @ 2064384
    //   khb    512*768 bf16 -> 196608 @ 2359296
    //   vhT    768*512 bf16 -> 196608 @ 2555904
    //   rwkeysb 512*768 bf16 -> 196608 @ 2752512
    //   qrwb   512*768 bf16 -> 196608 @ 2949120   (end 3145728 f = 12.6 MB)
    float* S0 = mem_out;
    u16*   memb    = (u16*)(S0 + 0);
    u16*   csb     = (u16*)(S0 + 196608);
    u16*   ipwb    = (u16*)(S0 + 294912);
    u16*   rwb     = (u16*)(S0 + 1179648);
    u16*   wwwb    = (u16*)(S0 + 1474560);
    u16*   ewb     = (u16*)(S0 + 1769472);
    u16*   outwb   = (u16*)(S0 + 2064384);
    u16*   khb     = (u16*)(S0 + 2359296);
    u16*   vhT     = (u16*)(S0 + 2555904);
    u16*   rwkeysb = (u16*)(S0 + 2752512);
    u16*   qrwb    = (u16*)(S0 + 2949120);

    // d_ws (f32 words; every offset %4==0):
    float* ws    = (float*)d_ws;
    float* erase = ws;                     // 196608 @ 0
    u16*   ctxb  = (u16*)(ws + 196608);    //  98304 @ 196608
    u16*   E     = (u16*)(ws + 294912);    // 1048576 @ 294912
    float* linv  =        ws + 1343488;    //   4096
    float* vg    =        ws + 1347584;    //   1536
    float* gc    =        ws + 1349120;    //     16
    float* delta =        ws + 1349136;    // 196608
    float* wwb   =        ws + 1545744;    // 131072 (end 1676816 f = 6.7 MB)

    conv_kernel<<<2328, 256, 0, stream>>>(mem, cs, ipw, rw, ww_w, ew, outw, outb,
                                          ugw, ugb, fgw, fgb,
                                          memb, csb, ipwb, rwb, wwwb, ewb, outwb,
                                          vg, gc);
    stage1_kernel<<<336, 256, 0, stream>>>(memb, csb, ipwb, ipb, rwb, rb, wwwb, ww_b,
                                           ewb, eb, khb, vhT, rwkeysb, erase);
    stage2_kernel<<<96, 256, 0, stream>>>(rwkeysb, ipwb, ipb, qrwb);
    scores_sm_kernel<<<dim3(8, 8), 256, 0, stream>>>(qrwb, khb, E, linv);
    pv_kernel<<<dim3(4, 2, 8), 256, 0, stream>>>(E, linv, vhT, ctxb);
    finalize_kernel<<<816, 256, 0, stream>>>(ctxb, outwb, outb, rd_out,
                                             cs, wdta, erase, ugw, fgw, vg, gc,
                                             E, linv, delta, wwb);
    update_mem<<<B_ * (M_ / 8), 192, 0, stream>>>(mem, wwb, delta, mem_out);
}

// Round 9
// 149.911 us; speedup vs baseline: 1.1576x; 1.0746x over previous
//
#include <hip/hip_runtime.h>
#include <math.h>

// Problem constants
#define B_ 256
#define M_ 512
#define D_ 768
#define H_ 8
#define DH_ 96
#define C_ 768

typedef float  f32x4_t __attribute__((ext_vector_type(4)));
typedef short  s16x8   __attribute__((ext_vector_type(8)));
typedef unsigned short u16;

__device__ __forceinline__ u16 cvt_bf16(float f) {
    union { float f; unsigned int u; } v; v.f = f;
    unsigned int r = (v.u + 0x7FFFu + ((v.u >> 16) & 1u)) >> 16;
    return (u16)r;
}
__device__ __forceinline__ float bf16_f32(u16 h) {
    union { unsigned int u; float f; } v; v.u = ((unsigned int)h) << 16;
    return v.f;
}

#define ACC_INIT {{0,0,0,0},{0,0,0,0},{0,0,0,0},{0,0,0,0}}
#define SCALE_ 0.10206207261596577f   // 1/sqrt(96)

// ---------------------------------------------------------------------------
// 64x64 bf16 MFMA GEMM core (proven R5): tile = A(64xK) @ B(64xK)^T.
// ---------------------------------------------------------------------------
template<int BK>
__device__ __forceinline__ void mm64b(
    const u16* __restrict__ A, int lda, const u16* __restrict__ B, int ldb,
    int ksteps, int bRowClamp, u16* lA, u16* lB, f32x4_t* acc, int nfrag)
{
    constexpr int NL = BK / 32;
    const int t = threadIdx.x;
    const int srow = t >> 2, kq = t & 3;
    const int l = t & 63, w = t >> 6;
    const int brow = srow < bRowClamp ? srow : bRowClamp;

    for (int ks = 0; ks < ksteps; ++ks) {
        s16x8 va[NL], vb[NL];
        #pragma unroll
        for (int c = 0; c < NL; ++c) {
            const int ko = ks * BK + (kq * NL + c) * 8;
            va[c] = *reinterpret_cast<const s16x8*>(A + (size_t)srow * lda + ko);
            vb[c] = *reinterpret_cast<const s16x8*>(B + (size_t)brow * ldb + ko);
        }
        __syncthreads();
        #pragma unroll
        for (int c = 0; c < NL; ++c) {
            const int kb = kq * NL + c;
            *reinterpret_cast<s16x8*>(lA + (kb * 64 + srow) * 8) = va[c];
            *reinterpret_cast<s16x8*>(lB + (kb * 64 + srow) * 8) = vb[c];
        }
        __syncthreads();
        #pragma unroll
        for (int ksub = 0; ksub < NL; ++ksub) {
            const int kb = (l >> 4) + ksub * 4;
            s16x8 af = *reinterpret_cast<const s16x8*>(lA + (kb * 64 + w * 16 + (l & 15)) * 8);
            #pragma unroll
            for (int nb = 0; nb < 4; ++nb) {
                if (nb < nfrag) {
                    s16x8 bf = *reinterpret_cast<const s16x8*>(lB + (kb * 64 + nb * 16 + (l & 15)) * 8);
                    acc[nb] = __builtin_amdgcn_mfma_f32_16x16x32_bf16(af, bf, acc[nb], 0, 0, 0);
                }
            }
        }
    }
}

// C/D layout: col = lane&15, row = (lane>>4)*4 + reg (within wave's 16-row slice).
__device__ __forceinline__ void epilogue_f32(
    const f32x4_t* acc, float* out, int ldo, int m0, int n0,
    const float* bias, int act, int nfrag)
{
    const int t = threadIdx.x, l = t & 63, w = t >> 6;
    const int mbase = m0 + w * 16 + (l >> 4) * 4;
    #pragma unroll
    for (int nb = 0; nb < 4; ++nb) {
        if (nb >= nfrag) break;
        const int col = n0 + nb * 16 + (l & 15);
        const float bv = bias ? bias[col] : 0.0f;
        #pragma unroll
        for (int r = 0; r < 4; ++r) {
            float v = acc[nb][r] + bv;
            if (act) v = 1.0f / (1.0f + expf(-v));
            out[(size_t)(mbase + r) * ldo + col] = v;
        }
    }
}

__device__ __forceinline__ void epilogue_bf16(
    const f32x4_t* acc, u16* out, int ldo, int m0, int n0,
    const float* bias, int nfrag)
{
    const int t = threadIdx.x, l = t & 63, w = t >> 6;
    const int mbase = m0 + w * 16 + (l >> 4) * 4;
    #pragma unroll
    for (int nb = 0; nb < 4; ++nb) {
        if (nb >= nfrag) break;
        const int col = n0 + nb * 16 + (l & 15);
        const float bv = bias ? bias[col] : 0.0f;
        #pragma unroll
        for (int r = 0; r < 4; ++r)
            out[(size_t)(mbase + r) * ldo + col] = cvt_bf16(acc[nb][r] + bv);
    }
}

// ---------------------------------------------------------------------------
// L1 conv (2328 blocks): f32->bf16 conversions (2304) + vg/gc GEMV (24).
// ---------------------------------------------------------------------------
__global__ __launch_bounds__(256) void conv_kernel(
    const float* __restrict__ mem, const float* __restrict__ cs,
    const float* __restrict__ ipw, const float* __restrict__ rw,
    const float* __restrict__ www, const float* __restrict__ ew,
    const float* __restrict__ outw, const float* __restrict__ outb,
    const float* __restrict__ ugw, const float* __restrict__ ugb,
    const float* __restrict__ fgw, const float* __restrict__ fgb,
    u16* __restrict__ memb, u16* __restrict__ csb, u16* __restrict__ ipwb,
    u16* __restrict__ rwb, u16* __restrict__ wwwb, u16* __restrict__ ewb,
    u16* __restrict__ outwb, float* __restrict__ vg, float* __restrict__ gc)
{
    __shared__ float sred[256];
    const int bid = blockIdx.x, t = threadIdx.x;

    if (bid < 2304) {
        const float* src; u16* dst; int base;
        if      (bid < 192)  { src = mem;  dst = memb;  base = bid; }
        else if (bid < 288)  { src = cs;   dst = csb;   base = bid - 192; }
        else if (bid < 1152) { src = ipw;  dst = ipwb;  base = bid - 288; }
        else if (bid < 1440) { src = rw;   dst = rwb;   base = bid - 1152; }
        else if (bid < 1728) { src = www;  dst = wwwb;  base = bid - 1440; }
        else if (bid < 2016) { src = ew;   dst = ewb;   base = bid - 1728; }
        else                 { src = outw; dst = outwb; base = bid - 2016; }
        const size_t i = ((size_t)base * 256 + t) * 8;
        float4 x = *reinterpret_cast<const float4*>(src + i);
        float4 y = *reinterpret_cast<const float4*>(src + i + 4);
        s16x8 o;
        o[0]=cvt_bf16(x.x); o[1]=cvt_bf16(x.y); o[2]=cvt_bf16(x.z); o[3]=cvt_bf16(x.w);
        o[4]=cvt_bf16(y.x); o[5]=cvt_bf16(y.y); o[6]=cvt_bf16(y.z); o[7]=cvt_bf16(y.w);
        *reinterpret_cast<s16x8*>(dst + i) = o;
    } else {
        const int lid = bid - 2304;
        const int v = lid / 12, kt = lid % 12;
        const float* gw = v == 0 ? ugw : fgw;
        const int c = t & 63, g = t >> 6;
        const int col = kt * 64 + c;
        float acc = 0.f;
        #pragma unroll 4
        for (int i = 0; i < 192; ++i) {
            const int row = g * 192 + i;
            acc += outw[(size_t)row * 768 + col] * gw[768 + row];
        }
        sred[t] = acc;
        __syncthreads();
        if (g == 0)
            vg[v * 768 + col] = sred[c] + sred[64 + c] + sred[128 + c] + sred[192 + c];
        if (kt == 0) {
            __syncthreads();
            float cp = outb[t] * gw[768 + t] + outb[t + 256] * gw[768 + t + 256]
                     + outb[t + 512] * gw[768 + t + 512];
            sred[t] = cp; __syncthreads();
            #pragma unroll
            for (int off = 128; off > 0; off >>= 1) {
                if (t < off) sred[t] += sred[t + off];
                __syncthreads();
            }
            if (t == 0) gc[v] = sred[0] + (v == 0 ? ugb[0] : fgb[0]);
        }
    }
}

// ---------------------------------------------------------------------------
// L2 stage1 (336 blocks): kh+vhT (192), read keys (48), write keys (48), erase (48)
// ---------------------------------------------------------------------------
__global__ __launch_bounds__(256) void stage1_kernel(
    const u16* __restrict__ memb, const u16* __restrict__ csb,
    const u16* __restrict__ ipwb, const float* __restrict__ ipb,
    const u16* __restrict__ rwb, const float* __restrict__ rb,
    const u16* __restrict__ wwwb, const float* __restrict__ ww_b,
    const u16* __restrict__ ewb, const float* __restrict__ eb,
    u16* __restrict__ khb, u16* __restrict__ vhT,
    u16* __restrict__ rwkeysb, float* __restrict__ erase)
{
    __shared__ u16 lA[8192], lB[8192];
    f32x4_t acc[4] = ACC_INIT;
    const int bid = blockIdx.x;
    if (bid < 192) {
        const int mt = bid / 24, nt = bid % 24;
        mm64b<64>(memb + (size_t)mt * 64 * 768, 768,
                  ipwb + (size_t)768 * 768 + (size_t)nt * 64 * 768, 768,
                  12, 63, lA, lB, acc, 4);
        const int t = threadIdx.x, l = t & 63, w = t >> 6;
        const int mbase = mt * 64 + w * 16 + (l >> 4) * 4;
        if (nt < 12) {
            #pragma unroll
            for (int nb = 0; nb < 4; ++nb) {
                const int col = nt * 64 + nb * 16 + (l & 15);
                const float bv = ipb[768 + col];
                #pragma unroll
                for (int r = 0; r < 4; ++r)
                    khb[(size_t)(mbase + r) * 768 + col] = cvt_bf16(acc[nb][r] + bv);
            }
        } else {
            #pragma unroll
            for (int nb = 0; nb < 4; ++nb) {
                const int cg = (nt - 12) * 64 + nb * 16 + (l & 15);   // 0..767
                const int h = cg / 96, d = cg % 96;
                const float bv = ipb[1536 + cg];
                u16* dst = vhT + ((size_t)h * 96 + d) * 512;
                #pragma unroll
                for (int r = 0; r < 4; ++r)
                    dst[mbase + r] = cvt_bf16(acc[nb][r] + bv);
            }
        }
    } else if (bid < 240) {
        const int lid = bid - 192, mt = lid / 12, nt = lid % 12;
        mm64b<64>(csb + (size_t)mt * 64 * 768, 768, rwb + (size_t)nt * 64 * 768, 768,
                  12, 63, lA, lB, acc, 4);
        epilogue_bf16(acc, rwkeysb, 768, mt * 64, nt * 64, rb, 4);
    } else if (bid < 288) {
        const int lid = bid - 240, mt = lid / 12, nt = lid % 12;
        mm64b<64>(csb + (size_t)mt * 64 * 768, 768, wwwb + (size_t)nt * 64 * 768, 768,
                  12, 63, lA, lB, acc, 4);
        epilogue_bf16(acc, rwkeysb + (size_t)256 * 768, 768, mt * 64, nt * 64, ww_b, 4);
    } else {
        const int lid = bid - 288, mt = lid / 12, nt = lid % 12;
        mm64b<64>(csb + (size_t)mt * 64 * 768, 768, ewb + (size_t)nt * 64 * 768, 768,
                  12, 63, lA, lB, acc, 4);
        epilogue_f32(acc, erase, 768, mt * 64, nt * 64, eb, 1, 4);
    }
}

// ---------------------------------------------------------------------------
// L3 stage2 (96 blocks): qrw = rwkeys(512x768) @ wq^T + bq -> bf16
// ---------------------------------------------------------------------------
__global__ __launch_bounds__(256) void stage2_kernel(
    const u16* __restrict__ rwkeysb, const u16* __restrict__ ipwb,
    const float* __restrict__ ipb, u16* __restrict__ qrwb)
{
    __shared__ u16 lA[8192], lB[8192];
    f32x4_t acc[4] = ACC_INIT;
    const int mt = blockIdx.x / 12, nt = blockIdx.x % 12;
    mm64b<64>(rwkeysb + (size_t)mt * 64 * 768, 768, ipwb + (size_t)nt * 64 * 768, 768,
              12, 63, lA, lB, acc, 4);
    epilogue_bf16(acc, qrwb, 768, mt * 64, nt * 64, ipb, 4);
}

// ---------------------------------------------------------------------------
// L4 scores (grid (64,8) = 512 blocks): E[h][q][m] = exp(min(q.k*scale,30)) bf16
// (unnormalized; clamp never binds on valid data — scores std ~0.1)
// ---------------------------------------------------------------------------
__global__ __launch_bounds__(256) void scores_kernel(
    const u16* __restrict__ qrwb, const u16* __restrict__ khb, u16* __restrict__ E)
{
    __shared__ u16 lA[2048], lB[2048];
    f32x4_t acc[4] = ACC_INIT;
    const int h = blockIdx.y;
    const int mt = blockIdx.x >> 3, nt = blockIdx.x & 7;
    mm64b<32>(qrwb + (size_t)mt * 64 * 768 + h * 96, 768,
              khb + (size_t)nt * 64 * 768 + h * 96, 768, 3, 63, lA, lB, acc, 4);
    const int t = threadIdx.x, l = t & 63, w = t >> 6;
    const int mbase = mt * 64 + w * 16 + (l >> 4) * 4;     // q
    #pragma unroll
    for (int nb = 0; nb < 4; ++nb) {
        const int col = nt * 64 + nb * 16 + (l & 15);       // m
        #pragma unroll
        for (int r = 0; r < 4; ++r) {
            const float e = expf(fminf(acc[nb][r] * SCALE_, 30.0f));
            E[((size_t)h * 512 + mbase + r) * 512 + col] = cvt_bf16(e);
        }
    }
}

// ---------------------------------------------------------------------------
// L5 PV (grid (4,2,8)): ctx = (E_rows/rowsum) @ vhT^T -> ctxb bf16.
// Row sums computed during staging (each row's K is read by 4 threads).
// ---------------------------------------------------------------------------
__global__ __launch_bounds__(256) void pv_kernel(
    const u16* __restrict__ E, const u16* __restrict__ vhT, u16* __restrict__ ctxb)
{
    __shared__ u16 lA[8192], lB[8192];
    __shared__ float rinv[64];
    f32x4_t acc[4] = ACC_INIT;
    const int h = blockIdx.z, mt = blockIdx.x, nt = blockIdx.y;
    const int n0 = nt * 64;
    const int nfrag = nt == 0 ? 4 : 2;
    const int bclamp = nt == 0 ? 63 : 31;

    const u16* A  = E + ((size_t)h * 512 + mt * 64) * 512;   // q rows 0..255
    const u16* Bv = vhT + ((size_t)h * 96 + n0) * 512;

    const int t = threadIdx.x;
    const int srow = t >> 2, kq = t & 3;
    const int l = t & 63, w = t >> 6;
    const int brow = srow < bclamp ? srow : bclamp;

    float rs = 0.f;                                           // partial row sum
    for (int ks = 0; ks < 8; ++ks) {
        s16x8 va[2], vb[2];
        #pragma unroll
        for (int c = 0; c < 2; ++c) {
            const int ko = ks * 64 + (kq * 2 + c) * 8;
            va[c] = *reinterpret_cast<const s16x8*>(A + (size_t)srow * 512 + ko);
            vb[c] = *reinterpret_cast<const s16x8*>(Bv + (size_t)brow * 512 + ko);
        }
        #pragma unroll
        for (int c = 0; c < 2; ++c)
            #pragma unroll
            for (int j = 0; j < 8; ++j)
                rs += bf16_f32((u16)va[c][j]);
        __syncthreads();
        #pragma unroll
        for (int c = 0; c < 2; ++c) {
            const int kb = kq * 2 + c;
            *reinterpret_cast<s16x8*>(lA + (kb * 64 + srow) * 8) = va[c];
            *reinterpret_cast<s16x8*>(lB + (kb * 64 + srow) * 8) = vb[c];
        }
        __syncthreads();
        #pragma unroll
        for (int ksub = 0; ksub < 2; ++ksub) {
            const int kb = (l >> 4) + ksub * 4;
            s16x8 af = *reinterpret_cast<const s16x8*>(lA + (kb * 64 + w * 16 + (l & 15)) * 8);
            #pragma unroll
            for (int nb = 0; nb < 4; ++nb) {
                if (nb < nfrag) {
                    s16x8 bf = *reinterpret_cast<const s16x8*>(lB + (kb * 64 + nb * 16 + (l & 15)) * 8);
                    acc[nb] = __builtin_amdgcn_mfma_f32_16x16x32_bf16(af, bf, acc[nb], 0, 0, 0);
                }
            }
        }
    }
    // reduce rs over the 4 staging threads of each row (same wave: lanes 4s..4s+3)
    rs += __shfl_xor(rs, 1);
    rs += __shfl_xor(rs, 2);
    if (kq == 0) rinv[srow] = 1.0f / rs;
    __syncthreads();

    const int mbase = w * 16 + (l >> 4) * 4;                 // local row 0..63
    #pragma unroll
    for (int nb = 0; nb < 4; ++nb) {
        if (nb >= nfrag) break;
        const int col = n0 + nb * 16 + (l & 15);
        #pragma unroll
        for (int r = 0; r < 4; ++r) {
            const float v = acc[nb][r] * rinv[mbase + r];
            ctxb[(size_t)(mt * 64 + mbase + r) * 768 + h * 96 + col] = cvt_bf16(v);
        }
    }
}

// ---------------------------------------------------------------------------
// L6 finalize (560 blocks): [0,48) outproj; [48,304) gates+delta;
// [304,560) ww per-batch (normalizes write rows itself).
// ---------------------------------------------------------------------------
__global__ __launch_bounds__(256) void finalize_kernel(
    const u16* __restrict__ ctxb, const u16* __restrict__ outwb,
    const float* __restrict__ outb, float* __restrict__ rd_out,
    const float* __restrict__ cs, const float* __restrict__ wdta,
    const float* __restrict__ erase,
    const float* __restrict__ ugw, const float* __restrict__ fgw,
    const float* __restrict__ vg, const float* __restrict__ gc,
    const u16* __restrict__ E,
    float* __restrict__ delta, float* __restrict__ wwb)
{
    __shared__ u16 lA[8192], lB[8192];
    const int bid = blockIdx.x, t = threadIdx.x;
    if (bid < 48) {
        f32x4_t acc[4] = ACC_INIT;
        const int mt = bid / 12, nt = bid % 12;
        mm64b<64>(ctxb + (size_t)mt * 64 * 768, 768, outwb + (size_t)nt * 64 * 768, 768,
                  12, 63, lA, lB, acc, 4);
        epilogue_f32(acc, rd_out, 768, mt * 64, nt * 64, outb, 0, 4);
    } else if (bid < 304) {
        const int b = bid - 48;
        __shared__ float red[8];
        float pu = 0.f, pf = 0.f;
        #pragma unroll
        for (int c = 0; c < 3; ++c) {
            const int i = t + c * 256;
            const float cv = cs[(size_t)b * 768 + i];
            const float xv = bf16_f32(ctxb[(size_t)b * 768 + i]);
            pu += cv * ugw[i] + xv * vg[i];
            pf += cv * fgw[i] + xv * vg[768 + i];
        }
        const int w = t >> 6, l = t & 63;
        #pragma unroll
        for (int off = 32; off > 0; off >>= 1) {
            pu += __shfl_xor(pu, off);
            pf += __shfl_xor(pf, off);
        }
        if (l == 0) { red[w] = pu; red[4 + w] = pf; }
        __syncthreads();
        const float ug = 1.0f / (1.0f + expf(-(red[0] + red[1] + red[2] + red[3] + gc[0])));
        const float fg = 1.0f / (1.0f + expf(-(red[4] + red[5] + red[6] + red[7] + gc[1])));
        #pragma unroll
        for (int c = 0; c < 3; ++c) {
            const int i = t + c * 256;
            delta[(size_t)b * 768 + i] = wdta[(size_t)b * 768 + i] * ug
                                       - erase[(size_t)b * 768 + i] * fg;
        }
    } else {
        // ww[b][m] = 0.125 * sum_h E[h][256+b][m] / rowsum(h, 256+b)
        const int b = bid - 304;
        __shared__ float linv8[8];
        const int w = t >> 6, l = t & 63;
        #pragma unroll
        for (int hh = 0; hh < 2; ++hh) {
            const int h = w * 2 + hh;
            const u16* row = E + ((size_t)h * 512 + 256 + b) * 512;
            float s = 0.f;
            #pragma unroll
            for (int c = 0; c < 8; ++c) s += bf16_f32(row[c * 64 + l]);
            #pragma unroll
            for (int off = 32; off > 0; off >>= 1) s += __shfl_xor(s, off);
            if (l == 0) linv8[h] = 1.0f / s;
        }
        __syncthreads();
        #pragma unroll
        for (int mm_ = 0; mm_ < 2; ++mm_) {
            const int m = t + mm_ * 256;
            float s = 0.f;
            #pragma unroll
            for (int h = 0; h < H_; ++h)
                s += bf16_f32(E[((size_t)h * 512 + 256 + b) * 512 + m]) * linv8[h];
            wwb[(size_t)b * 512 + m] = s * 0.125f;
        }
    }
}

// ---------------------------------------------------------------------------
// L7 memory update (403 MB writer): out = mem + ww*delta, NT stores. Runs last.
// ---------------------------------------------------------------------------
__global__ __launch_bounds__(192) void update_mem(
    const float* __restrict__ mem, const float* __restrict__ ww,
    const float* __restrict__ delta, float* __restrict__ out)
{
    const int blk = blockIdx.x;
    const int b   = blk >> 6;
    const int m0  = (blk & 63) << 3;
    const int t   = threadIdx.x;

    const f32x4_t d4 = *reinterpret_cast<const f32x4_t*>(delta + (size_t)b * D_ + t * 4);
    const f32x4_t* m4 = reinterpret_cast<const f32x4_t*>(mem);
    f32x4_t* o4 = reinterpret_cast<f32x4_t*>(out + (size_t)b * M_ * D_);

    #pragma unroll
    for (int i = 0; i < 8; ++i) {
        const int m = m0 + i;
        const float w = ww[(size_t)b * M_ + m];
        f32x4_t mm = m4[(size_t)m * 192 + t];
        f32x4_t r = mm + w * d4;
        __builtin_nontemporal_store(r, &o4[(size_t)m * 192 + t]);
    }
}

// ---------------------------------------------------------------------------
extern "C" void kernel_launch(void* const* d_in, const int* in_sizes, int n_in,
                              void* d_out, int out_size, void* d_ws, size_t ws_size,
                              hipStream_t stream)
{
    const float* cs   = (const float*)d_in[0];
    const float* wdta = (const float*)d_in[1];
    const float* mem  = (const float*)d_in[2];
    const float* ipw  = (const float*)d_in[3];
    const float* ipb  = (const float*)d_in[4];
    const float* outw = (const float*)d_in[5];
    const float* outb = (const float*)d_in[6];
    const float* rw   = (const float*)d_in[7];
    const float* rb   = (const float*)d_in[8];
    const float* ww_w = (const float*)d_in[9];
    const float* ww_b = (const float*)d_in[10];
    const float* ew   = (const float*)d_in[11];
    const float* eb   = (const float*)d_in[12];
    const float* ugw  = (const float*)d_in[13];
    const float* ugb  = (const float*)d_in[14];
    const float* fgw  = (const float*)d_in[15];
    const float* fgb  = (const float*)d_in[16];

    float* rd_out  = (float*)d_out;              // read_data (B, D)
    float* mem_out = (float*)d_out + B_ * D_;    // updated_memory (B, M, D)

    // Scratch in mem_out region (dead until update_mem; update_mem reads only
    // inputs + d_ws). Offsets in f32 WORDS (u16 count / 2), all %4==0.
    float* S0 = mem_out;
    u16*   memb    = (u16*)(S0 + 0);         // 512*768 bf16  -> 196608 f
    u16*   csb     = (u16*)(S0 + 196608);    // 256*768 bf16  ->  98304 f
    u16*   ipwb    = (u16*)(S0 + 294912);    // 2304*768 bf16 -> 884736 f
    u16*   rwb     = (u16*)(S0 + 1179648);   // 768*768 bf16  -> 294912 f
    u16*   wwwb    = (u16*)(S0 + 1474560);   // 768*768 bf16  -> 294912 f
    u16*   ewb     = (u16*)(S0 + 1769472);   // 768*768 bf16  -> 294912 f
    u16*   outwb   = (u16*)(S0 + 2064384);   // 768*768 bf16  -> 294912 f
    u16*   khb     = (u16*)(S0 + 2359296);   // 512*768 bf16  -> 196608 f
    u16*   vhT     = (u16*)(S0 + 2555904);   // 768*512 bf16  -> 196608 f
    u16*   rwkeysb = (u16*)(S0 + 2752512);   // 512*768 bf16  -> 196608 f
    u16*   qrwb    = (u16*)(S0 + 2949120);   // 512*768 bf16  -> 196608 f (end 3145728)

    // d_ws (f32 words; all offsets %4==0):
    float* ws    = (float*)d_ws;
    float* erase = ws;                       // 196608 @ 0
    u16*   ctxb  = (u16*)(ws + 196608);      //  98304 @ 196608
    u16*   E     = (u16*)(ws + 294912);      // 8*512*512 bf16 -> 1048576 @ 294912
    float* vg    =        ws + 1343488;      //   1536
    float* gc    =        ws + 1345024;      //     16
    float* delta =        ws + 1345040;      // 196608
    float* wwb   =        ws + 1541648;      // 131072 (end 1672720 f = 6.7 MB)

    conv_kernel<<<2328, 256, 0, stream>>>(mem, cs, ipw, rw, ww_w, ew, outw, outb,
                                          ugw, ugb, fgw, fgb,
                                          memb, csb, ipwb, rwb, wwwb, ewb, outwb,
                                          vg, gc);
    stage1_kernel<<<336, 256, 0, stream>>>(memb, csb, ipwb, ipb, rwb, rb, wwwb, ww_b,
                                           ewb, eb, khb, vhT, rwkeysb, erase);
    stage2_kernel<<<96, 256, 0, stream>>>(rwkeysb, ipwb, ipb, qrwb);
    scores_kernel<<<dim3(64, 8), 256, 0, stream>>>(qrwb, khb, E);
    pv_kernel<<<dim3(4, 2, 8), 256, 0, stream>>>(E, vhT, ctxb);
    finalize_kernel<<<560, 256, 0, stream>>>(ctxb, outwb, outb, rd_out,
                                             cs, wdta, erase, ugw, fgw, vg, gc,
                                             E, delta, wwb);
    update_mem<<<B_ * (M_ / 8), 192, 0, stream>>>(mem, wwb, delta, mem_out);
}